// Round 7
// baseline (510.037 us; speedup 1.0000x reference)
//
#include <hip/hip_runtime.h>
#include <hip/hip_bf16.h>

#define B_   256
#define S_   2048
#define DIN  128
#define H_   64
#define SD_  5
#define TILE 16
#define NT   (S_ / TILE)
#define TOKB 256   // tokens per phaseA block
#define NIT  4     // tiles per wave (4 waves x 16 tokens x 4 = 256)

typedef __attribute__((ext_vector_type(8))) short short8_t;   // 8 bf16
typedef __attribute__((ext_vector_type(4))) float float4_t;   // MFMA acc

__device__ __forceinline__ float rcpf_(float x){ return __builtin_amdgcn_rcpf(x); }

// exact-erf GELU: gelu(x)=0.5x(1+erf(x/sqrt2)), A&S 7.1.26
__device__ __forceinline__ float geluf(float v){
  const float kInvSqrt2 = 0.70710678118654752440f;
  float z = v * kInvSqrt2;
  float a = fabsf(z);
  float t = rcpf_(fmaf(0.3275911f, a, 1.0f));
  float p = fmaf(fmaf(fmaf(fmaf(1.061405429f, t, -1.453152027f), t, 1.421413741f),
                      t, -0.284496736f), t, 0.254829592f);
  p *= t;
  float e = 1.0f - p * __expf(-z * z);
  float er = copysignf(e, z);
  return 0.5f * v * (1.0f + er);
}

__device__ __forceinline__ float sigmoidf_(float x){
  return rcpf_(1.0f + __expf(-x));
}

// Pade(3,2) tanh with clamp: |err| <= 0.0065 (attenuated x0.01 by corr_scale)
__device__ __forceinline__ float tanh_pade(float x){
  float xc = fminf(fmaxf(x, -4.0f), 4.0f);
  float t = xc * xc;
  float n = xc * (27.0f + t);
  float d = fmaf(9.0f, t, 27.0f);
  return n * rcpf_(d);
}

__device__ __forceinline__ unsigned short f2bf_hw(float f){
  union { __hip_bfloat16 b; unsigned short u; } cv;
  cv.b = __float2bfloat16(f);
  return cv.u;
}
__device__ __forceinline__ float bf2f(unsigned short h){
  return __uint_as_float(((unsigned int)h) << 16);
}

// ---- async global->LDS ----
__device__ __forceinline__ void gl_lds16(const void* g, void* l){
  __builtin_amdgcn_global_load_lds(
      (const __attribute__((address_space(1))) void*)g,
      (__attribute__((address_space(3))) void*)l, 16, 0, 0);
}
__device__ __forceinline__ void gl_lds4(const void* g, void* l){
  __builtin_amdgcn_global_load_lds(
      (const __attribute__((address_space(1))) void*)g,
      (__attribute__((address_space(3))) void*)l, 4, 0, 0);
}

// ---- DPP helpers ----
template<int CTRL>
__device__ __forceinline__ float dpp_radd(float x){
  int sh = __builtin_amdgcn_update_dpp(0, __float_as_int(x), CTRL, 0xf, 0xf, true);
  return x + __int_as_float(sh);
}
// all-lane sum within each 16-lane row: quad xor1, xor2, then ror4, ror8
__device__ __forceinline__ float red16(float x){
  x = dpp_radd<0xB1>(x);   // quad_perm [1,0,3,2]  (xor 1)
  x = dpp_radd<0x4E>(x);   // quad_perm [2,3,0,1]  (xor 2)
  x = dpp_radd<0x124>(x);  // row_ror:4
  x = dpp_radd<0x128>(x);  // row_ror:8
  return x;
}

// ---------------------------------------------------------------------------
// Phase A (unchanged from round 6, MFMA-based)
// ---------------------------------------------------------------------------
__global__ __launch_bounds__(256, 4) void phaseA(
    const float* __restrict__ x, const float* __restrict__ W_in,
    const float* __restrict__ b_in, const float* __restrict__ ln_g,
    const float* __restrict__ ln_b, const float* __restrict__ W_innov,
    const float* __restrict__ b_innov, const float* __restrict__ W_c1,
    const float* __restrict__ b_c1,
    unsigned short* __restrict__ hp_out, float* __restrict__ bx_out)
{
  __shared__ __align__(16) unsigned short WfA[4][4][512];
  __shared__ __align__(16) unsigned short WfC[2][4][512];
  __shared__ __align__(16) unsigned short WfI[2][512];
  __shared__ __align__(16) unsigned short hbuf[4][16][72];

  const int tid  = threadIdx.x;
  const int lane = tid & 63;
  const int w    = tid >> 6;
  const int c16  = lane & 15;
  const int g4   = lane >> 4;
  const long tok0 = (long)blockIdx.x * TOKB;

  {
    const int l = lane, tg = w;
    #pragma unroll
    for (int pp = 0; pp < 4; ++pp){
      int p  = tg * 4 + pp;
      int kc = p >> 2, nc = p & 3;
      unsigned short tmp[8];
      #pragma unroll
      for (int m = 0; m < 8; ++m)
        tmp[m] = f2bf_hw(W_in[(32 * kc + 8 * (l >> 4) + m) * 64 + 16 * nc + (l & 15)]);
      *(uint4*)&WfA[kc][nc][l * 8] = *(uint4*)tmp;
    }
    #pragma unroll
    for (int pp = 0; pp < 2; ++pp){
      int p  = tg * 2 + pp;
      int kc2 = p >> 2, nc = p & 3;
      unsigned short tmp[8];
      #pragma unroll
      for (int m = 0; m < 8; ++m)
        tmp[m] = f2bf_hw(W_c1[(5 + 32 * kc2 + 8 * (l >> 4) + m) * 64 + 16 * nc + (l & 15)]);
      *(uint4*)&WfC[kc2][nc][l * 8] = *(uint4*)tmp;
    }
    if (tg < 2){
      int kc2 = tg;
      unsigned short tmp[8];
      #pragma unroll
      for (int m = 0; m < 8; ++m)
        tmp[m] = ((l & 15) < 5)
               ? f2bf_hw(W_innov[(32 * kc2 + 8 * (l >> 4) + m) * 5 + (l & 15)])
               : (unsigned short)0;
      *(uint4*)&WfI[kc2][l * 8] = *(uint4*)tmp;
    }
  }

  float binv[4], lg[4], lb[4], bc1v[4];
  #pragma unroll
  for (int nc = 0; nc < 4; ++nc){
    binv[nc] = b_in[16 * nc + c16];
    lg[nc]   = ln_g[16 * nc + c16];
    lb[nc]   = ln_b[16 * nc + c16];
    bc1v[nc] = b_c1[16 * nc + c16];
  }
  float binn = (c16 < 5) ? b_innov[c16] : 0.0f;

  __syncthreads();

  for (int it = 0; it < NIT; ++it){
    const long tbg = tok0 + it * 64 + w * 16;

    const float* xr = x + (size_t)(tbg + c16) * DIN;
    short8_t a1[4];
    #pragma unroll
    for (int kc = 0; kc < 4; ++kc){
      float4 f0 = *(const float4*)(xr + kc * 32 + g4 * 8);
      float4 f1 = *(const float4*)(xr + kc * 32 + g4 * 8 + 4);
      a1[kc][0] = (short)f2bf_hw(f0.x); a1[kc][1] = (short)f2bf_hw(f0.y);
      a1[kc][2] = (short)f2bf_hw(f0.z); a1[kc][3] = (short)f2bf_hw(f0.w);
      a1[kc][4] = (short)f2bf_hw(f1.x); a1[kc][5] = (short)f2bf_hw(f1.y);
      a1[kc][6] = (short)f2bf_hw(f1.z); a1[kc][7] = (short)f2bf_hw(f1.w);
    }

    float4_t acc1[4] = {{0,0,0,0},{0,0,0,0},{0,0,0,0},{0,0,0,0}};
    #pragma unroll
    for (int kc = 0; kc < 4; ++kc){
      #pragma unroll
      for (int nc = 0; nc < 4; ++nc){
        short8_t bf = *(const short8_t*)&WfA[kc][nc][lane * 8];
        acc1[nc] = __builtin_amdgcn_mfma_f32_16x16x32_bf16(a1[kc], bf, acc1[nc], 0, 0, 0);
      }
    }

    float v[4][4];
    #pragma unroll
    for (int nc = 0; nc < 4; ++nc)
      #pragma unroll
      for (int r = 0; r < 4; ++r)
        v[nc][r] = acc1[nc][r] + binv[nc];

    float mu[4], rstd[4];
    #pragma unroll
    for (int r = 0; r < 4; ++r){
      float vs = (v[0][r] + v[1][r]) + (v[2][r] + v[3][r]);
      float qs = v[0][r] * v[0][r];
      qs = fmaf(v[1][r], v[1][r], qs);
      qs = fmaf(v[2][r], v[2][r], qs);
      qs = fmaf(v[3][r], v[3][r], qs);
      vs = red16(vs);
      qs = red16(qs);
      float m  = vs * (1.0f / 64.0f);
      float va = fmaxf(qs * (1.0f / 64.0f) - m * m, 0.0f);
      mu[r]   = m;
      rstd[r] = rsqrtf(va + 1e-5f);
    }

    #pragma unroll
    for (int nc = 0; nc < 4; ++nc)
      #pragma unroll
      for (int r = 0; r < 4; ++r){
        float hn = fmaf((v[nc][r] - mu[r]) * rstd[r], lg[nc], lb[nc]);
        hbuf[w][4 * g4 + r][16 * nc + c16] = f2bf_hw(geluf(hn));
      }

    short8_t a2[2];
    a2[0] = *(const short8_t*)&hbuf[w][c16][8 * g4];
    a2[1] = *(const short8_t*)&hbuf[w][c16][32 + 8 * g4];

    float4_t acc2[4] = {{0,0,0,0},{0,0,0,0},{0,0,0,0},{0,0,0,0}};
    #pragma unroll
    for (int kc2 = 0; kc2 < 2; ++kc2){
      #pragma unroll
      for (int nc = 0; nc < 4; ++nc){
        short8_t bf = *(const short8_t*)&WfC[kc2][nc][lane * 8];
        acc2[nc] = __builtin_amdgcn_mfma_f32_16x16x32_bf16(a2[kc2], bf, acc2[nc], 0, 0, 0);
      }
    }
    float4_t acc3 = {0, 0, 0, 0};
    {
      short8_t bi0 = *(const short8_t*)&WfI[0][lane * 8];
      short8_t bi1 = *(const short8_t*)&WfI[1][lane * 8];
      acc3 = __builtin_amdgcn_mfma_f32_16x16x32_bf16(a2[0], bi0, acc3, 0, 0, 0);
      acc3 = __builtin_amdgcn_mfma_f32_16x16x32_bf16(a2[1], bi1, acc3, 0, 0, 0);
    }

    if (c16 < 5){
      #pragma unroll
      for (int r = 0; r < 4; ++r)
        bx_out[(size_t)(tbg + 4 * g4 + r) * 8 + c16] = acc3[r] + binn;
    }

    #pragma unroll
    for (int nc = 0; nc < 4; ++nc)
      #pragma unroll
      for (int r = 0; r < 4; ++r)
        hbuf[w][4 * g4 + r][16 * nc + c16] = f2bf_hw(acc2[nc][r] + bc1v[nc]);

    {
      const int tl = lane >> 2, j = lane & 3;
      uint4 v0 = *(const uint4*)&hbuf[w][tl][j * 16];
      uint4 v1 = *(const uint4*)&hbuf[w][tl][j * 16 + 8];
      unsigned short* hg = hp_out + (size_t)(tbg + tl) * 64 + j * 16;
      *(uint4*)hg       = v0;
      *(uint4*)(hg + 8) = v1;
    }
  }
}

// ---------------------------------------------------------------------------
// Phase B: TWO chains per wave (register-parallel), delayed injection GD=16
// (A^16 twist, one group per 16-step tile), XOR-swizzled u staging, MFMA corr.
// ---------------------------------------------------------------------------
__global__ __launch_bounds__(64, 1) void phaseB(
    const unsigned short* __restrict__ hp, const float* __restrict__ bx,
    const float* __restrict__ W_c1, const float* __restrict__ W_c2,
    const float* __restrict__ b_c2, const float* __restrict__ corr_scale,
    const float* __restrict__ rawL, const float* __restrict__ rawT,
    const float* __restrict__ rawG, const float* __restrict__ rawR,
    const float* __restrict__ omega, float* __restrict__ out)
{
  __shared__ __align__(16) unsigned short hpT[2][2][TILE][64];  // [buf][chain] 8 KB
  __shared__ __align__(16) float bxT[2][2][TILE][8];            // 2 KB
  __shared__ __align__(16) unsigned short uT[2][TILE][64];      // [chain] 4 KB, swizzled cols
  __shared__ __align__(16) float crL[2][TILE][8];               // [chain] 1 KB

  const int lane = threadIdx.x;
  const int b2 = blockIdx.x;          // handles batch rows 2*b2, 2*b2+1
  const int c16 = lane & 15;
  const int g4  = lane >> 4;

  // zero-init corrections
  *(float4*)&((float*)crL)[lane * 4] = make_float4(0.f, 0.f, 0.f, 0.f);

  float aL = sigmoidf_(rawL[0]) * 0.15f + 0.85f;
  float aT = sigmoidf_(rawT[0]) * 0.25f + 0.70f;
  float gg = sigmoidf_(rawG[0]) * 0.20f + 0.80f;
  float om = omega[0];
  float co = cosf(om), sn = sinf(om);
  float r00 = gg * co, r01 = -gg * sn, r10 = gg * sn, r11 = gg * co;
  float aR = sigmoidf_(rawR[0]) * 0.4f;
  float cs = corr_scale[0];

  // A^16 for delayed injection
  float t2, aL16, aT16, aR16, g16;
  t2 = aL * aL; t2 = t2 * t2; t2 = t2 * t2; aL16 = t2 * t2;
  t2 = aT * aT; t2 = t2 * t2; t2 = t2 * t2; aT16 = t2 * t2;
  t2 = aR * aR; t2 = t2 * t2; t2 = t2 * t2; aR16 = t2 * t2;
  t2 = gg * gg; t2 = t2 * t2; t2 = t2 * t2; g16  = t2 * t2;
  float ck = cosf(16.0f * om), sk = sinf(16.0f * om);
  float p00 = g16 * ck, p01 = -g16 * sk, p10 = g16 * sk, p11 = g16 * ck;

  float w0 = W_c1[0 * 64 + lane], w1 = W_c1[1 * 64 + lane], w2 = W_c1[2 * 64 + lane];
  float w3 = W_c1[3 * 64 + lane], w4 = W_c1[4 * 64 + lane];
  float bc0 = b_c2[0], bc1 = b_c2[1], bc2v = b_c2[2], bc3 = b_c2[3], bc4 = b_c2[4];
  float bcs0 = (g4 == 1) ? bc4 : bc0;   // acc reg0 = row i=4*g4

  // static A-frags: W_c2^T (rows i=c16<5 else 0), K split j 0..31 / 32..63
  short8_t aF0, aF1;
  #pragma unroll
  for (int m = 0; m < 8; ++m){
    int j0 = 8 * g4 + m;
    float v0 = (c16 < 5) ? W_c2[j0 * 5 + c16] : 0.0f;
    float v1 = (c16 < 5) ? W_c2[(j0 + 32) * 5 + c16] : 0.0f;
    aF0[m] = (short)f2bf_hw(v0);
    aF1[m] = (short)f2bf_hw(v1);
  }

  const unsigned short* hpgA = hp + (size_t)(2 * b2 + 0) * S_ * H_;
  const unsigned short* hpgB = hp + (size_t)(2 * b2 + 1) * S_ * H_;
  const float* bxgA = bx + (size_t)(2 * b2 + 0) * S_ * 8;
  const float* bxgB = bx + (size_t)(2 * b2 + 1) * S_ * 8;

  float sA0 = 0.f, sA1 = 0.f, sA2 = 0.f, sA3 = 0.f, sA4 = 0.f;
  float sB0 = 0.f, sB1 = 0.f, sB2 = 0.f, sB3 = 0.f, sB4 = 0.f;

  auto ISSUE = [&](int t, int nb){
    const unsigned short* gA = hpgA + (size_t)t * (TILE * 64) + lane * 8;
    gl_lds16(gA,       &hpT[nb][0][0][0]);
    gl_lds16(gA + 512, &hpT[nb][0][8][0]);
    const unsigned short* gB = hpgB + (size_t)t * (TILE * 64) + lane * 8;
    gl_lds16(gB,       &hpT[nb][1][0][0]);
    gl_lds16(gB + 512, &hpT[nb][1][8][0]);
    const float* fA = bxgA + (size_t)t * (TILE * 8) + lane;
    gl_lds4(fA,      &bxT[nb][0][0][0]);
    gl_lds4(fA + 64, &bxT[nb][0][8][0]);
    const float* fB = bxgB + (size_t)t * (TILE * 8) + lane;
    gl_lds4(fB,      &bxT[nb][1][0][0]);
    gl_lds4(fB + 64, &bxT[nb][1][8][0]);
  };

  int buf = 0;
  ISSUE(0, 0);
  for (int t = 0; t < NT; ++t){
    int tn = (t + 1 < NT) ? (t + 1) : 0;
    ISSUE(tn, buf ^ 1);
    asm volatile("s_waitcnt vmcnt(8)" ::: "memory");
    __builtin_amdgcn_sched_barrier(0);

    // ---- 16-step recursion for both chains; stage u (swizzled) ----
    #pragma unroll
    for (int k = 0; k < TILE; ++k){
      float  hA  = bf2f(hpT[buf][0][k][lane]);
      float4 xbA = *(const float4*)&bxT[buf][0][k][0];
      float  eA  = bxT[buf][0][k][4];
      float4 cpA = *(const float4*)&crL[0][k][0];
      float  cA4 = crL[0][k][4];
      float  hB  = bf2f(hpT[buf][1][k][lane]);
      float4 xbB = *(const float4*)&bxT[buf][1][k][0];
      float  eB  = bxT[buf][1][k][4];
      float4 cpB = *(const float4*)&crL[1][k][0];
      float  cB4 = crL[1][k][4];

      float iA0 = fmaf(cpA.x, aL16, xbA.x);
      float iA1 = fmaf(cpA.y, aT16, xbA.y);
      float iA2 = fmaf(cpA.z, p00, fmaf(cpA.w, p10, xbA.z));
      float iA3 = fmaf(cpA.z, p01, fmaf(cpA.w, p11, xbA.w));
      float iA4 = fmaf(cA4, aR16, eA);
      float iB0 = fmaf(cpB.x, aL16, xbB.x);
      float iB1 = fmaf(cpB.y, aT16, xbB.y);
      float iB2 = fmaf(cpB.z, p00, fmaf(cpB.w, p10, xbB.z));
      float iB3 = fmaf(cpB.z, p01, fmaf(cpB.w, p11, xbB.w));
      float iB4 = fmaf(cB4, aR16, eB);

      float nA0 = fmaf(sA0, aL, iA0);
      float nA1 = fmaf(sA1, aT, iA1);
      float nA2 = fmaf(sA2, r00, fmaf(sA3, r10, iA2));
      float nA3 = fmaf(sA2, r01, fmaf(sA3, r11, iA3));
      float nA4 = fmaf(sA4, aR, iA4);
      sA0 = nA0; sA1 = nA1; sA2 = nA2; sA3 = nA3; sA4 = nA4;
      float nB0 = fmaf(sB0, aL, iB0);
      float nB1 = fmaf(sB1, aT, iB1);
      float nB2 = fmaf(sB2, r00, fmaf(sB3, r10, iB2));
      float nB3 = fmaf(sB2, r01, fmaf(sB3, r11, iB3));
      float nB4 = fmaf(sB4, aR, iB4);
      sB0 = nB0; sB1 = nB1; sB2 = nB2; sB3 = nB3; sB4 = nB4;

      float upA = fmaf(nA0, w0, hA);
      upA = fmaf(nA1, w1, upA); upA = fmaf(nA2, w2, upA);
      upA = fmaf(nA3, w3, upA); upA = fmaf(nA4, w4, upA);
      float uA = upA * rcpf_(1.0f + __expf(-1.702f * upA));
      float upB = fmaf(nB0, w0, hB);
      upB = fmaf(nB1, w1, upB); upB = fmaf(nB2, w2, upB);
      upB = fmaf(nB3, w3, upB); upB = fmaf(nB4, w4, upB);
      float uB = upB * rcpf_(1.0f + __expf(-1.702f * upB));

      const int jsw = lane ^ ((k & 7) << 3);   // XOR col-block swizzle
      uT[0][k][jsw] = (unsigned short)(__float_as_uint(uA) >> 16);
      uT[1][k][jsw] = (unsigned short)(__float_as_uint(uB) >> 16);
    }

    // ---- correction matmul + publish (per chain) ----
    #pragma unroll
    for (int c = 0; c < 2; ++c){
      const int blk0 = (g4 ^ (c16 & 7)) * 8;
      const int blk1 = (((4 + g4) ^ (c16 & 7))) * 8;
      short8_t b0 = *(const short8_t*)&uT[c][c16][blk0];
      short8_t b1 = *(const short8_t*)&uT[c][c16][blk1];
      float4_t acc = {0.f, 0.f, 0.f, 0.f};
      acc = __builtin_amdgcn_mfma_f32_16x16x32_bf16(aF0, b0, acc, 0, 0, 0);
      acc = __builtin_amdgcn_mfma_f32_16x16x32_bf16(aF1, b1, acc, 0, 0, 0);

      float d0 = cs * tanh_pade(acc[0] + bcs0);
      float d1 = cs * tanh_pade(acc[1] + bc1);
      float d2 = cs * tanh_pade(acc[2] + bc2v);
      float d3 = cs * tanh_pade(acc[3] + bc3);

      if (g4 == 0)
        *(float4*)&crL[c][c16][0] = make_float4(d0, d1, d2, d3);  // i=0..3, k=c16
      if (g4 == 1)
        crL[c][c16][4] = d0;                                      // i=4
    }
    buf ^= 1;
  }

  // ---- tail: s_final = s_hat + Horner(last 16 corrections under A) ----
  #pragma unroll
  for (int c = 0; c < 2; ++c){
    float v0 = crL[c][0][0], v1 = crL[c][0][1], v2 = crL[c][0][2],
          v3 = crL[c][0][3], v4 = crL[c][0][4];
    #pragma unroll
    for (int k = 1; k < TILE; ++k){
      float n0 = fmaf(v0, aL, crL[c][k][0]);
      float n1 = fmaf(v1, aT, crL[c][k][1]);
      float n2 = fmaf(v2, r00, fmaf(v3, r10, crL[c][k][2]));
      float n3 = fmaf(v2, r01, fmaf(v3, r11, crL[c][k][3]));
      float n4 = fmaf(v4, aR, crL[c][k][4]);
      v0 = n0; v1 = n1; v2 = n2; v3 = n3; v4 = n4;
    }
    if (lane == 0){
      float* o = out + (size_t)(2 * b2 + c) * SD_;
      if (c == 0){
        o[0] = sA0 + v0; o[1] = sA1 + v1; o[2] = sA2 + v2;
        o[3] = sA3 + v3; o[4] = sA4 + v4;
      } else {
        o[0] = sB0 + v0; o[1] = sB1 + v1; o[2] = sB2 + v2;
        o[3] = sB3 + v3; o[4] = sB4 + v4;
      }
    }
  }
}

// ---------------------------------------------------------------------------
extern "C" void kernel_launch(void* const* d_in, const int* in_sizes, int n_in,
                              void* d_out, int out_size, void* d_ws, size_t ws_size,
                              hipStream_t stream)
{
  const float* x          = (const float*)d_in[0];
  const float* W_in       = (const float*)d_in[1];
  const float* b_in       = (const float*)d_in[2];
  const float* ln_g       = (const float*)d_in[3];
  const float* ln_b       = (const float*)d_in[4];
  const float* W_innov    = (const float*)d_in[5];
  const float* b_innov    = (const float*)d_in[6];
  const float* W_c1       = (const float*)d_in[7];
  const float* b_c1       = (const float*)d_in[8];
  const float* W_c2       = (const float*)d_in[9];
  const float* b_c2       = (const float*)d_in[10];
  const float* corr_scale = (const float*)d_in[11];
  const float* rawL       = (const float*)d_in[12];
  const float* rawT       = (const float*)d_in[13];
  const float* rawG       = (const float*)d_in[14];
  const float* rawR       = (const float*)d_in[15];
  const float* omega      = (const float*)d_in[16];

  unsigned short* hp = (unsigned short*)d_ws;
  float* bx = (float*)((char*)d_ws + (size_t)B_ * S_ * H_ * 2);

  int nblocksA = (B_ * S_) / TOKB;   // 2048
  phaseA<<<nblocksA, 256, 0, stream>>>(x, W_in, b_in, ln_g, ln_b,
                                       W_innov, b_innov, W_c1, b_c1, hp, bx);
  phaseB<<<B_ / 2, 64, 0, stream>>>(hp, bx, W_c1, W_c2, b_c2, corr_scale,
                                    rawL, rawT, rawG, rawR, omega, (float*)d_out);
}

// Round 8
// 348.129 us; speedup vs baseline: 1.4651x; 1.4651x over previous
//
#include <hip/hip_runtime.h>
#include <hip/hip_bf16.h>

#define B_   256
#define S_   2048
#define DIN  128
#define H_   64
#define SD_  5
#define TILE 16
#define NT   (S_ / TILE)
#define GD   8
#define TOKB 256   // tokens per phaseA block
#define NIT  4     // tiles per wave (4 waves x 16 tokens x 4 = 256)

typedef __attribute__((ext_vector_type(8))) short short8_t;   // 8 bf16
typedef __attribute__((ext_vector_type(4))) float float4_t;   // MFMA acc

__device__ __forceinline__ float rcpf_(float x){ return __builtin_amdgcn_rcpf(x); }

// exact-erf GELU: gelu(x)=0.5x(1+erf(x/sqrt2)), A&S 7.1.26
__device__ __forceinline__ float geluf(float v){
  const float kInvSqrt2 = 0.70710678118654752440f;
  float z = v * kInvSqrt2;
  float a = fabsf(z);
  float t = rcpf_(fmaf(0.3275911f, a, 1.0f));
  float p = fmaf(fmaf(fmaf(fmaf(1.061405429f, t, -1.453152027f), t, 1.421413741f),
                      t, -0.284496736f), t, 0.254829592f);
  p *= t;
  float e = 1.0f - p * __expf(-z * z);
  float er = copysignf(e, z);
  return 0.5f * v * (1.0f + er);
}

__device__ __forceinline__ float sigmoidf_(float x){
  return rcpf_(1.0f + __expf(-x));
}

// Pade(3,2) tanh with clamp: |err| <= 0.0065 (attenuated x0.01 by corr_scale)
__device__ __forceinline__ float tanh_pade(float x){
  float xc = fminf(fmaxf(x, -4.0f), 4.0f);
  float t = xc * xc;
  float n = xc * (27.0f + t);
  float d = fmaf(9.0f, t, 27.0f);
  return n * rcpf_(d);
}

__device__ __forceinline__ unsigned short f2bf_hw(float f){
  union { __hip_bfloat16 b; unsigned short u; } cv;
  cv.b = __float2bfloat16(f);
  return cv.u;
}
__device__ __forceinline__ float bf2f(unsigned short h){
  return __uint_as_float(((unsigned int)h) << 16);
}

// ---- async global->LDS ----
__device__ __forceinline__ void gl_lds16(const void* g, void* l){
  __builtin_amdgcn_global_load_lds(
      (const __attribute__((address_space(1))) void*)g,
      (__attribute__((address_space(3))) void*)l, 16, 0, 0);
}
__device__ __forceinline__ void gl_lds4(const void* g, void* l){
  __builtin_amdgcn_global_load_lds(
      (const __attribute__((address_space(1))) void*)g,
      (__attribute__((address_space(3))) void*)l, 4, 0, 0);
}

// ---- DPP helpers ----
template<int CTRL>
__device__ __forceinline__ float dpp_radd(float x){
  int sh = __builtin_amdgcn_update_dpp(0, __float_as_int(x), CTRL, 0xf, 0xf, true);
  return x + __int_as_float(sh);
}
// all-lane sum within each 16-lane row: quad xor1, xor2, then ror4, ror8
__device__ __forceinline__ float red16(float x){
  x = dpp_radd<0xB1>(x);   // quad_perm [1,0,3,2]  (xor 1)
  x = dpp_radd<0x4E>(x);   // quad_perm [2,3,0,1]  (xor 2)
  x = dpp_radd<0x124>(x);  // row_ror:4
  x = dpp_radd<0x128>(x);  // row_ror:8
  return x;
}

// ---------------------------------------------------------------------------
// Phase A (unchanged, MFMA-based)
// ---------------------------------------------------------------------------
__global__ __launch_bounds__(256, 4) void phaseA(
    const float* __restrict__ x, const float* __restrict__ W_in,
    const float* __restrict__ b_in, const float* __restrict__ ln_g,
    const float* __restrict__ ln_b, const float* __restrict__ W_innov,
    const float* __restrict__ b_innov, const float* __restrict__ W_c1,
    const float* __restrict__ b_c1,
    unsigned short* __restrict__ hp_out, float* __restrict__ bx_out)
{
  __shared__ __align__(16) unsigned short WfA[4][4][512];
  __shared__ __align__(16) unsigned short WfC[2][4][512];
  __shared__ __align__(16) unsigned short WfI[2][512];
  __shared__ __align__(16) unsigned short hbuf[4][16][72];

  const int tid  = threadIdx.x;
  const int lane = tid & 63;
  const int w    = tid >> 6;
  const int c16  = lane & 15;
  const int g4   = lane >> 4;
  const long tok0 = (long)blockIdx.x * TOKB;

  {
    const int l = lane, tg = w;
    #pragma unroll
    for (int pp = 0; pp < 4; ++pp){
      int p  = tg * 4 + pp;
      int kc = p >> 2, nc = p & 3;
      unsigned short tmp[8];
      #pragma unroll
      for (int m = 0; m < 8; ++m)
        tmp[m] = f2bf_hw(W_in[(32 * kc + 8 * (l >> 4) + m) * 64 + 16 * nc + (l & 15)]);
      *(uint4*)&WfA[kc][nc][l * 8] = *(uint4*)tmp;
    }
    #pragma unroll
    for (int pp = 0; pp < 2; ++pp){
      int p  = tg * 2 + pp;
      int kc2 = p >> 2, nc = p & 3;
      unsigned short tmp[8];
      #pragma unroll
      for (int m = 0; m < 8; ++m)
        tmp[m] = f2bf_hw(W_c1[(5 + 32 * kc2 + 8 * (l >> 4) + m) * 64 + 16 * nc + (l & 15)]);
      *(uint4*)&WfC[kc2][nc][l * 8] = *(uint4*)tmp;
    }
    if (tg < 2){
      int kc2 = tg;
      unsigned short tmp[8];
      #pragma unroll
      for (int m = 0; m < 8; ++m)
        tmp[m] = ((l & 15) < 5)
               ? f2bf_hw(W_innov[(32 * kc2 + 8 * (l >> 4) + m) * 5 + (l & 15)])
               : (unsigned short)0;
      *(uint4*)&WfI[kc2][l * 8] = *(uint4*)tmp;
    }
  }

  float binv[4], lg[4], lb[4], bc1v[4];
  #pragma unroll
  for (int nc = 0; nc < 4; ++nc){
    binv[nc] = b_in[16 * nc + c16];
    lg[nc]   = ln_g[16 * nc + c16];
    lb[nc]   = ln_b[16 * nc + c16];
    bc1v[nc] = b_c1[16 * nc + c16];
  }
  float binn = (c16 < 5) ? b_innov[c16] : 0.0f;

  __syncthreads();

  for (int it = 0; it < NIT; ++it){
    const long tbg = tok0 + it * 64 + w * 16;

    const float* xr = x + (size_t)(tbg + c16) * DIN;
    short8_t a1[4];
    #pragma unroll
    for (int kc = 0; kc < 4; ++kc){
      float4 f0 = *(const float4*)(xr + kc * 32 + g4 * 8);
      float4 f1 = *(const float4*)(xr + kc * 32 + g4 * 8 + 4);
      a1[kc][0] = (short)f2bf_hw(f0.x); a1[kc][1] = (short)f2bf_hw(f0.y);
      a1[kc][2] = (short)f2bf_hw(f0.z); a1[kc][3] = (short)f2bf_hw(f0.w);
      a1[kc][4] = (short)f2bf_hw(f1.x); a1[kc][5] = (short)f2bf_hw(f1.y);
      a1[kc][6] = (short)f2bf_hw(f1.z); a1[kc][7] = (short)f2bf_hw(f1.w);
    }

    float4_t acc1[4] = {{0,0,0,0},{0,0,0,0},{0,0,0,0},{0,0,0,0}};
    #pragma unroll
    for (int kc = 0; kc < 4; ++kc){
      #pragma unroll
      for (int nc = 0; nc < 4; ++nc){
        short8_t bf = *(const short8_t*)&WfA[kc][nc][lane * 8];
        acc1[nc] = __builtin_amdgcn_mfma_f32_16x16x32_bf16(a1[kc], bf, acc1[nc], 0, 0, 0);
      }
    }

    float v[4][4];
    #pragma unroll
    for (int nc = 0; nc < 4; ++nc)
      #pragma unroll
      for (int r = 0; r < 4; ++r)
        v[nc][r] = acc1[nc][r] + binv[nc];

    float mu[4], rstd[4];
    #pragma unroll
    for (int r = 0; r < 4; ++r){
      float vs = (v[0][r] + v[1][r]) + (v[2][r] + v[3][r]);
      float qs = v[0][r] * v[0][r];
      qs = fmaf(v[1][r], v[1][r], qs);
      qs = fmaf(v[2][r], v[2][r], qs);
      qs = fmaf(v[3][r], v[3][r], qs);
      vs = red16(vs);
      qs = red16(qs);
      float m  = vs * (1.0f / 64.0f);
      float va = fmaxf(qs * (1.0f / 64.0f) - m * m, 0.0f);
      mu[r]   = m;
      rstd[r] = rsqrtf(va + 1e-5f);
    }

    #pragma unroll
    for (int nc = 0; nc < 4; ++nc)
      #pragma unroll
      for (int r = 0; r < 4; ++r){
        float hn = fmaf((v[nc][r] - mu[r]) * rstd[r], lg[nc], lb[nc]);
        hbuf[w][4 * g4 + r][16 * nc + c16] = f2bf_hw(geluf(hn));
      }

    short8_t a2[2];
    a2[0] = *(const short8_t*)&hbuf[w][c16][8 * g4];
    a2[1] = *(const short8_t*)&hbuf[w][c16][32 + 8 * g4];

    float4_t acc2[4] = {{0,0,0,0},{0,0,0,0},{0,0,0,0},{0,0,0,0}};
    #pragma unroll
    for (int kc2 = 0; kc2 < 2; ++kc2){
      #pragma unroll
      for (int nc = 0; nc < 4; ++nc){
        short8_t bf = *(const short8_t*)&WfC[kc2][nc][lane * 8];
        acc2[nc] = __builtin_amdgcn_mfma_f32_16x16x32_bf16(a2[kc2], bf, acc2[nc], 0, 0, 0);
      }
    }
    float4_t acc3 = {0, 0, 0, 0};
    {
      short8_t bi0 = *(const short8_t*)&WfI[0][lane * 8];
      short8_t bi1 = *(const short8_t*)&WfI[1][lane * 8];
      acc3 = __builtin_amdgcn_mfma_f32_16x16x32_bf16(a2[0], bi0, acc3, 0, 0, 0);
      acc3 = __builtin_amdgcn_mfma_f32_16x16x32_bf16(a2[1], bi1, acc3, 0, 0, 0);
    }

    if (c16 < 5){
      #pragma unroll
      for (int r = 0; r < 4; ++r)
        bx_out[(size_t)(tbg + 4 * g4 + r) * 8 + c16] = acc3[r] + binn;
    }

    #pragma unroll
    for (int nc = 0; nc < 4; ++nc)
      #pragma unroll
      for (int r = 0; r < 4; ++r)
        hbuf[w][4 * g4 + r][16 * nc + c16] = f2bf_hw(acc2[nc][r] + bc1v[nc]);

    {
      const int tl = lane >> 2, j = lane & 3;
      uint4 v0 = *(const uint4*)&hbuf[w][tl][j * 16];
      uint4 v1 = *(const uint4*)&hbuf[w][tl][j * 16 + 8];
      unsigned short* hg = hp_out + (size_t)(tbg + tl) * 64 + j * 16;
      *(uint4*)hg       = v0;
      *(uint4*)(hg + 8) = v1;
    }
  }
}

// ---------------------------------------------------------------------------
// Phase B: 1 chain/wave, 256 blocks, GD=8 delayed injection (A^8 twist),
// MFMA correction. Source is PHASE-BATCHED per 8-step group so the scheduler
// can pipeline independent work: LOAD-ALL -> I-ALL -> S-CHAIN -> UP-ALL ->
// GELU-ALL -> STAGE-ALL -> CORR. u staging is XOR-swizzled (bank-conflict
// floor). Tail recovers the last 8 corrections exactly via Horner.
// ---------------------------------------------------------------------------
__global__ __launch_bounds__(64, 1) void phaseB(
    const unsigned short* __restrict__ hp, const float* __restrict__ bx,
    const float* __restrict__ W_c1, const float* __restrict__ W_c2,
    const float* __restrict__ b_c2, const float* __restrict__ corr_scale,
    const float* __restrict__ rawL, const float* __restrict__ rawT,
    const float* __restrict__ rawG, const float* __restrict__ rawR,
    const float* __restrict__ omega, float* __restrict__ out)
{
  __shared__ __align__(16) unsigned short hpT[2][TILE][64];  // 4 KB
  __shared__ __align__(16) float bxT[2][TILE][8];            // 1 KB
  __shared__ __align__(16) unsigned short uT[TILE][64];      // 2 KB (swizzled)
  __shared__ __align__(16) float crLDS[8][8];                // 256 B

  const int lane = threadIdx.x;
  const int b = blockIdx.x;
  const int c16 = lane & 15;
  const int g4  = lane >> 4;

  // zero-init crLDS and uT rows 8..15 (cols 8..15 of the MFMA B-operand)
  if (lane < 16) *(float4*)&((float*)crLDS)[lane * 4] = make_float4(0.f,0.f,0.f,0.f);
  *(uint4*)((char*)uT + 1024 + lane * 16) = make_uint4(0u,0u,0u,0u);

  float aL = sigmoidf_(rawL[0]) * 0.15f + 0.85f;
  float aT = sigmoidf_(rawT[0]) * 0.25f + 0.70f;
  float gg = sigmoidf_(rawG[0]) * 0.20f + 0.80f;
  float om = omega[0];
  float co = cosf(om), sn = sinf(om);
  float r00 = gg * co, r01 = -gg * sn, r10 = gg * sn, r11 = gg * co;
  float aR = sigmoidf_(rawR[0]) * 0.4f;
  float cs = corr_scale[0];

  // A^8 for delayed injection
  float t2, aL8, aT8, aR8, g8;
  t2 = aL * aL;  t2 = t2 * t2;  aL8 = t2 * t2;
  t2 = aT * aT;  t2 = t2 * t2;  aT8 = t2 * t2;
  t2 = aR * aR;  t2 = t2 * t2;  aR8 = t2 * t2;
  t2 = gg * gg;  t2 = t2 * t2;  g8  = t2 * t2;
  float c8 = cosf(8.0f * om), s8 = sinf(8.0f * om);
  float q00 = g8 * c8, q01 = -g8 * s8, q10 = g8 * s8, q11 = g8 * c8;

  float w0 = W_c1[0 * 64 + lane], w1 = W_c1[1 * 64 + lane], w2 = W_c1[2 * 64 + lane];
  float w3 = W_c1[3 * 64 + lane], w4 = W_c1[4 * 64 + lane];
  float bc0 = b_c2[0], bc1 = b_c2[1], bc2v = b_c2[2], bc3 = b_c2[3], bc4 = b_c2[4];
  float bcs0 = (g4 == 1) ? bc4 : bc0;   // acc reg0 = row i=4*g4

  // static A-frags: W_c2^T (rows i=c16<5 else 0), K split j 0..31 / 32..63
  short8_t aF0, aF1;
  #pragma unroll
  for (int m = 0; m < 8; ++m){
    int j0 = 8 * g4 + m;
    float v0 = (c16 < 5) ? W_c2[j0 * 5 + c16] : 0.0f;
    float v1 = (c16 < 5) ? W_c2[(j0 + 32) * 5 + c16] : 0.0f;
    aF0[m] = (short)f2bf_hw(v0);
    aF1[m] = (short)f2bf_hw(v1);
  }

  const unsigned short* hpg = hp + (size_t)b * S_ * H_;
  const float* bxg = bx + (size_t)b * S_ * 8;

  float s0 = 0.f, s1 = 0.f, s2 = 0.f, s3 = 0.f, s4 = 0.f;

  auto ISSUE = [&](int t, int nb){
    const unsigned short* g0 = hpg + (size_t)t * (TILE * 64) + lane * 8;
    gl_lds16(g0,       &hpT[nb][0][0]);
    gl_lds16(g0 + 512, &hpT[nb][8][0]);
    const float* g1 = bxg + (size_t)t * (TILE * 8) + lane;
    gl_lds4(g1,      &bxT[nb][0][0]);
    gl_lds4(g1 + 64, &bxT[nb][8][0]);
  };

  int buf = 0;
  ISSUE(0, 0);
  for (int t = 0; t < NT; ++t){
    int tn = (t + 1 < NT) ? (t + 1) : 0;
    ISSUE(tn, buf ^ 1);
    asm volatile("s_waitcnt vmcnt(4)" ::: "memory");
    __builtin_amdgcn_sched_barrier(0);

    #pragma unroll
    for (int g = 0; g < 2; ++g){
      const int base = g * GD;

      // ---- LOAD-ALL: previous-group corrections + this group's operands ----
      float4 cp[GD]; float cp4[GD];
      #pragma unroll
      for (int k = 0; k < GD; ++k){
        cp[k]  = *(const float4*)&crLDS[k][0];
        cp4[k] = crLDS[k][4];
      }
      float hk[GD], e4v[GD]; float4 xb[GD];
      #pragma unroll
      for (int k = 0; k < GD; ++k){
        hk[k]  = bf2f(hpT[buf][base + k][lane]);
        xb[k]  = *(const float4*)&bxT[buf][base + k][0];
        e4v[k] = bxT[buf][base + k][4];
      }

      // ---- I-ALL: injected inputs, independent across k ----
      float i0[GD], i1[GD], i2[GD], i3[GD], i4[GD];
      #pragma unroll
      for (int k = 0; k < GD; ++k){
        i0[k] = fmaf(cp[k].x, aL8, xb[k].x);
        i1[k] = fmaf(cp[k].y, aT8, xb[k].y);
        i2[k] = fmaf(cp[k].z, q00, fmaf(cp[k].w, q10, xb[k].z));
        i3[k] = fmaf(cp[k].z, q01, fmaf(cp[k].w, q11, xb[k].w));
        i4[k] = fmaf(cp4[k], aR8, e4v[k]);
      }

      // ---- S-CHAIN: short serial recursion, record all states ----
      float n0[GD], n1[GD], n2[GD], n3[GD], n4[GD];
      #pragma unroll
      for (int k = 0; k < GD; ++k){
        n0[k] = fmaf(s0, aL, i0[k]);
        n1[k] = fmaf(s1, aT, i1[k]);
        n2[k] = fmaf(s2, r00, fmaf(s3, r10, i2[k]));
        n3[k] = fmaf(s2, r01, fmaf(s3, r11, i3[k]));
        n4[k] = fmaf(s4, aR, i4[k]);
        s0 = n0[k]; s1 = n1[k]; s2 = n2[k]; s3 = n3[k]; s4 = n4[k];
      }

      // ---- UP-ALL: 8 independent 5-deep chains ----
      float up[GD];
      #pragma unroll
      for (int k = 0; k < GD; ++k){
        float u = fmaf(n0[k], w0, hk[k]);
        u = fmaf(n1[k], w1, u);
        u = fmaf(n2[k], w2, u);
        u = fmaf(n3[k], w3, u);
        up[k] = fmaf(n4[k], w4, u);
      }

      // ---- GELU-ALL (sigmoid-GELU) ----
      float uu[GD];
      #pragma unroll
      for (int k = 0; k < GD; ++k)
        uu[k] = up[k] * rcpf_(1.0f + __expf(-1.702f * up[k]));

      // ---- STAGE-ALL: bf16, XOR-swizzled columns ----
      #pragma unroll
      for (int k = 0; k < GD; ++k){
        const int jsw = lane ^ ((k & 7) << 3);
        uT[k][jsw] = (unsigned short)(__float_as_uint(uu[k]) >> 16);
      }

      // ---- CORR: 2 x MFMA + tanh + publish ----
      {
        const int blk0 = (g4 ^ (c16 & 7)) * 8;
        const int blk1 = ((4 + g4) ^ (c16 & 7)) * 8;
        short8_t b0 = *(const short8_t*)&uT[c16][blk0];
        short8_t b1 = *(const short8_t*)&uT[c16][blk1];
        float4_t acc = {0.f, 0.f, 0.f, 0.f};
        acc = __builtin_amdgcn_mfma_f32_16x16x32_bf16(aF0, b0, acc, 0, 0, 0);
        acc = __builtin_amdgcn_mfma_f32_16x16x32_bf16(aF1, b1, acc, 0, 0, 0);

        float d0 = cs * tanh_pade(acc[0] + bcs0);
        float d1 = cs * tanh_pade(acc[1] + bc1);
        float d2 = cs * tanh_pade(acc[2] + bc2v);
        float d3 = cs * tanh_pade(acc[3] + bc3);

        if (lane < 8)
          *(float4*)&crLDS[lane][0] = make_float4(d0, d1, d2, d3);  // i=0..3, k=lane
        if (g4 == 1 && c16 < 8)
          crLDS[c16][4] = d0;                                       // i=4
      }
    }
    buf ^= 1;
  }

  // ---- tail: s_final = s_hat + Horner(last 8 corrections under A) ----
  float4 cl[GD]; float cl4[GD];
  #pragma unroll
  for (int k = 0; k < GD; ++k){
    cl[k]  = *(const float4*)&crLDS[k][0];
    cl4[k] = crLDS[k][4];
  }
  float v0 = cl[0].x, v1 = cl[0].y, v2 = cl[0].z, v3 = cl[0].w, v4 = cl4[0];
  #pragma unroll
  for (int k = 1; k < GD; ++k){
    float n0 = fmaf(v0, aL, cl[k].x);
    float n1 = fmaf(v1, aT, cl[k].y);
    float n2 = fmaf(v2, r00, fmaf(v3, r10, cl[k].z));
    float n3 = fmaf(v2, r01, fmaf(v3, r11, cl[k].w));
    float n4 = fmaf(v4, aR, cl4[k]);
    v0 = n0; v1 = n1; v2 = n2; v3 = n3; v4 = n4;
  }

  if (lane == 0){
    float* o = out + b * SD_;
    o[0] = s0 + v0; o[1] = s1 + v1; o[2] = s2 + v2;
    o[3] = s3 + v3; o[4] = s4 + v4;
  }
}

// ---------------------------------------------------------------------------
extern "C" void kernel_launch(void* const* d_in, const int* in_sizes, int n_in,
                              void* d_out, int out_size, void* d_ws, size_t ws_size,
                              hipStream_t stream)
{
  const float* x          = (const float*)d_in[0];
  const float* W_in       = (const float*)d_in[1];
  const float* b_in       = (const float*)d_in[2];
  const float* ln_g       = (const float*)d_in[3];
  const float* ln_b       = (const float*)d_in[4];
  const float* W_innov    = (const float*)d_in[5];
  const float* b_innov    = (const float*)d_in[6];
  const float* W_c1       = (const float*)d_in[7];
  const float* b_c1       = (const float*)d_in[8];
  const float* W_c2       = (const float*)d_in[9];
  const float* b_c2       = (const float*)d_in[10];
  const float* corr_scale = (const float*)d_in[11];
  const float* rawL       = (const float*)d_in[12];
  const float* rawT       = (const float*)d_in[13];
  const float* rawG       = (const float*)d_in[14];
  const float* rawR       = (const float*)d_in[15];
  const float* omega      = (const float*)d_in[16];

  unsigned short* hp = (unsigned short*)d_ws;
  float* bx = (float*)((char*)d_ws + (size_t)B_ * S_ * H_ * 2);

  int nblocksA = (B_ * S_) / TOKB;   // 2048
  phaseA<<<nblocksA, 256, 0, stream>>>(x, W_in, b_in, ln_g, ln_b,
                                       W_innov, b_innov, W_c1, b_c1, hp, bx);
  phaseB<<<B_, 64, 0, stream>>>(hp, bx, W_c1, W_c2, b_c2, corr_scale,
                                rawL, rawT, rawG, rawR, omega, (float*)d_out);
}